// Round 12
// baseline (92.551 us; speedup 1.0000x reference)
//
#include <hip/hip_runtime.h>
#include <utility>

// reference == inverse(M M^T + EPS*I) per pixel, M = x[b,:,:,h,w]^T (16x64)
// x: [B=4, C=64, K=16, H=128, W=128] f32 ; out: [B,H,W,16,16] f32
// Fused, 32 px/block, 2048 blocks (2x the 4-blocks/CU residency -> generation
// staggering: late blocks' gram overlaps early blocks' inversion+store tail).
//   phase 1: gram via global_load_lds dbuf (8KB chunks = 4c x 16k x 32px),
//            2-way pair split BY WAVE (wave-uniform templates); px = lane&31,
//            upper half-lanes duplicate px 0..31 via LDS broadcast (free).
//   phase 2: lanes 0-31 of each wave -> tri[136][35] (+EPS diag)
//   phase 3: threads 0-31: tri -> REGISTER Cholesky -> L^-1 -> M^T M -> tri
//   phase 4: 128 threads gather-store coalesced (2 elements each, 32 px)
// LDS: union{stage 2x8KB, tri 19KB} = 19KB; VGPR (~190) caps 4 blocks/CU.

#define EPSR 1e-6f
#define TS 35                      // tri row stride (coprime-ish banks, 19 KB)

__device__ __host__ constexpr int rowof(int t) {
    int i = 0;
    while ((i + 1) * (i + 2) / 2 <= t) ++i;
    return i;
}
__device__ __host__ constexpr int colof(int t) { return t - rowof(t) * (rowof(t) + 1) / 2; }

__device__ __forceinline__ constexpr int tidx(int i, int j) {  // i >= j
    return i * (i + 1) / 2 + j;
}

#define GLOAD_LDS16(gp, lp)                                                       \
    __builtin_amdgcn_global_load_lds(                                             \
        (const __attribute__((address_space(1))) void*)(gp),                      \
        (__attribute__((address_space(3))) void*)(lp), 16, 0, 0)

// ---------------- pair-split template machinery (68/wave) ----------------

template<int P>
__device__ __forceinline__ void fma_pair(const float (&m)[16], float& a) {
    a = fmaf(m[rowof(P)], m[colof(P)], a);
}

template<int G, int... TT>
__device__ __forceinline__ void fma_group(const float (&m)[16], float (&acc)[68],
                                          std::integer_sequence<int, TT...>) {
    (fma_pair<G * 68 + TT>(m, acc[TT]), ...);
}

template<int G>
__device__ __forceinline__ void chunk_fma4(const float* __restrict__ buf, int px,
                                           float (&acc)[68]) {
    #pragma unroll
    for (int crel = 0; crel < 4; ++crel) {
        float m[16];
        #pragma unroll
        for (int k = 0; k < 16; ++k) m[k] = buf[crel * 512 + k * 32 + px];
        fma_group<G>(m, acc, std::make_integer_sequence<int, 68>{});
    }
}

template<int P>
__device__ __forceinline__ void store_tri_pair(float* __restrict__ tri, int px, float v) {
    constexpr bool diag = (rowof(P) == colof(P));
    tri[P * TS + px] = diag ? (v + EPSR) : v;
}

template<int G, int... TT>
__device__ __forceinline__ void store_tri_group(float* __restrict__ tri, int px,
                                                const float (&acc)[68],
                                                std::integer_sequence<int, TT...>) {
    (store_tri_pair<G * 68 + TT>(tri, px, acc[TT]), ...);
}

// ---------------- fused kernel ----------------

union SMem {
    float stage[2][2048];      // 2 x 8 KB: [crel(0..3)*512 + k*32 + px]
    float tri[136 * TS];       // 19 KB; row = pair index, col = pixel (32 used)
};

__global__ __launch_bounds__(128, 2)
void fused_gram_inv(const float* __restrict__ x, float* __restrict__ out) {
    __shared__ __align__(16) SMem sm;

    const int tid = threadIdx.x;
    const int lane = tid & 63;
    const int wv = tid >> 6;                  // 0 or 1
    const int px = lane & 31;                 // both half-waves mirror px 0..31
    const int p0 = blockIdx.x * 32;
    const int b = blockIdx.x >> 9;            // 512 blocks per batch
    const int hw0 = p0 & 16383;

    // staging src: lane l covers k-row (l>>3), px (l&7)*4..+3  (16B/lane)
    const float* gbase = x + (size_t)b * 16777216 + hw0
                           + (size_t)(lane >> 3) * 16384 + (size_t)(lane & 7) * 4;

    float acc[68];
    #pragma unroll
    for (int t = 0; t < 68; ++t) acc[t] = 0.0f;

    // chunk = channels [c0, c0+4); wave wv stages c = c0 + 2wv + s (2 instrs each)
    auto STAGE = [&](int bufi, int c0) {
        #pragma unroll
        for (int s = 0; s < 2; ++s) {
            const int crel = 2 * wv + s;
            const float* gp = gbase + (size_t)(c0 + crel) * 262144;
            #pragma unroll
            for (int q = 0; q < 2; ++q) {
                GLOAD_LDS16(gp + (size_t)(q * 8) * 16384,
                            &sm.stage[bufi][crel * 512 + q * 256]);
            }
        }
    };

    // ---- phase 1: gram, dbuf pipeline (16 chunks of 4 c) ----
    STAGE(0, 0);
    for (int t = 0; t < 16; ++t) {
        __syncthreads();                              // vmcnt(0) drain + barrier
        if (t < 15) STAGE((t + 1) & 1, 4 * (t + 1));  // prefetch next chunk
        const float* buf = sm.stage[t & 1];
        if (wv == 0) chunk_fma4<0>(buf, px, acc);
        else         chunk_fma4<1>(buf, px, acc);
    }
    __syncthreads();   // all stage reads done before aliasing stage as tri

    // ---- phase 2: lanes 0-31 -> tri (+EPS on diag); waves: disjoint rows ----
    if (lane < 32) {
        if (wv == 0) store_tri_group<0>(sm.tri, px, acc, std::make_integer_sequence<int, 68>{});
        else         store_tri_group<1>(sm.tri, px, acc, std::make_integer_sequence<int, 68>{});
    }
    __syncthreads();

    // ---- phase 3: threads 0-31, lane = pixel, REGISTER inversion ----
    if (tid < 32) {
        float s[136];
        #pragma unroll
        for (int t = 0; t < 136; ++t) s[t] = sm.tri[t * TS + tid];

        // Cholesky in place: off-diag = L[i][j], diag = 1/L[j][j]
        #pragma unroll
        for (int j = 0; j < 16; ++j) {
            float d = s[tidx(j, j)];
            #pragma unroll
            for (int q = 0; q < j; ++q) d = fmaf(-s[tidx(j, q)], s[tidx(j, q)], d);
            const float invd = 1.0f / sqrtf(d);
            s[tidx(j, j)] = invd;
            #pragma unroll
            for (int i = j + 1; i < 16; ++i) {
                float v = s[tidx(i, j)];
                #pragma unroll
                for (int q = 0; q < j; ++q) v = fmaf(-s[tidx(i, q)], s[tidx(j, q)], v);
                s[tidx(i, j)] = v * invd;
            }
        }

        // M = L^{-1} in place (diag already inverted)
        #pragma unroll
        for (int j = 0; j < 16; ++j) {
            #pragma unroll
            for (int i = j + 1; i < 16; ++i) {
                float sum = s[tidx(i, j)] * s[tidx(j, j)];
                #pragma unroll
                for (int q = j + 1; q < i; ++q)
                    sum = fmaf(s[tidx(i, q)], s[tidx(q, j)], sum);
                s[tidx(i, j)] = -s[tidx(i, i)] * sum;
            }
        }

        // A^{-1} = M^T M in place
        #pragma unroll
        for (int j = 0; j < 16; ++j) {
            #pragma unroll
            for (int i = j; i < 16; ++i) {
                float sum = 0.0f;
                #pragma unroll
                for (int q = i; q < 16; ++q)
                    sum = fmaf(s[tidx(q, i)], s[tidx(q, j)], sum);
                s[tidx(i, j)] = sum;
            }
        }

        // writeback
        #pragma unroll
        for (int t = 0; t < 136; ++t) sm.tri[t * TS + tid] = s[t];
    }
    __syncthreads();

    // ---- phase 4: gather-store, each thread: elements tid and tid+128 ----
    const int e0 = tid;                 // 0..127
    const int e1 = tid + 128;           // 128..255
    const int i0 = e0 >> 4, j0 = e0 & 15;
    const int h0 = i0 > j0 ? i0 : j0, l0 = i0 + j0 - h0;
    const int trow0 = h0 * (h0 + 1) / 2 + l0;
    const int i1 = e1 >> 4, j1 = e1 & 15;
    const int h1 = i1 > j1 ? i1 : j1, l1 = i1 + j1 - h1;
    const int trow1 = h1 * (h1 + 1) / 2 + l1;

    float* gout = out + (size_t)p0 * 256;
    #pragma unroll 8
    for (int a = 0; a < 32; ++a) {
        gout[(size_t)a * 256 + e0] = sm.tri[trow0 * TS + a];
        gout[(size_t)a * 256 + e1] = sm.tri[trow1 * TS + a];
    }
}

extern "C" void kernel_launch(void* const* d_in, const int* in_sizes, int n_in,
                              void* d_out, int out_size, void* d_ws, size_t ws_size,
                              hipStream_t stream) {
    const float* x = (const float*)d_in[0];
    float* out = (float*)d_out;
    hipLaunchKernelGGL(fused_gram_inv, dim3(2048), dim3(128), 0, stream, x, out);
}

// Round 13
// 70.885 us; speedup vs baseline: 1.3056x; 1.3056x over previous
//
#include <hip/hip_runtime.h>
#include <utility>

// reference == inverse(M M^T + EPS*I) per pixel, M = x[b,:,:,h,w]^T (16x64)
// x: [B=4, C=64, K=16, H=128, W=128] f32 ; out: [B,H,W,16,16] f32
// Fused, 128 px/block, 512 blocks, 256 threads (4 waves):
//   waves {0,1}: px 0-63 (lane=px), pair groups G0/G1 (68 pairs each, acc[68])
//   waves {2,3}: px 64-127, same split.
//   phase 1: gram via global_load_lds dbuf; chunk = 2c x 16k x 128px = 16 KB.
//            128-px blocks -> 512 B contiguous DRAM read per (c,k) row
//            (2x round-9's 256 B bursts; targets DRAM-burst efficiency).
//   phase 2: acc -> tri[136][131] (+EPS diag), disjoint (row,col) per wave
//   phase 3: waves 0,2: tri -> REGISTER Cholesky -> L^-1 -> M^T M -> tri
//   phase 4: 256 threads x 1 element, loop 128 px, 1 KB coalesced rows
// LDS: union{stage 2x16KB, tri 71.3KB} = 71.3KB -> 2 blocks/CU, 2 waves/SIMD.

#define EPSR 1e-6f
#define TS2 131                    // tri row stride; 131 mod 32 = 3 (bank spread)

__device__ __host__ constexpr int rowof(int t) {
    int i = 0;
    while ((i + 1) * (i + 2) / 2 <= t) ++i;
    return i;
}
__device__ __host__ constexpr int colof(int t) { return t - rowof(t) * (rowof(t) + 1) / 2; }

__device__ __forceinline__ constexpr int tidx(int i, int j) {  // i >= j
    return i * (i + 1) / 2 + j;
}

#define GLOAD_LDS16(gp, lp)                                                       \
    __builtin_amdgcn_global_load_lds(                                             \
        (const __attribute__((address_space(1))) void*)(gp),                      \
        (__attribute__((address_space(3))) void*)(lp), 16, 0, 0)

// ---------------- pair-split template machinery (68/group) ----------------

template<int P>
__device__ __forceinline__ void fma_pair(const float (&m)[16], float& a) {
    a = fmaf(m[rowof(P)], m[colof(P)], a);
}

template<int G, int... TT>
__device__ __forceinline__ void fma_group(const float (&m)[16], float (&acc)[68],
                                          std::integer_sequence<int, TT...>) {
    (fma_pair<G * 68 + TT>(m, acc[TT]), ...);
}

template<int G>
__device__ __forceinline__ void chunk_fma2(const float* __restrict__ buf, int px,
                                           float (&acc)[68]) {
    #pragma unroll
    for (int cs = 0; cs < 2; ++cs) {
        float m[16];
        #pragma unroll
        for (int k = 0; k < 16; ++k) m[k] = buf[cs * 2048 + k * 128 + px];
        fma_group<G>(m, acc, std::make_integer_sequence<int, 68>{});
    }
}

template<int P>
__device__ __forceinline__ void store_tri_pair(float* __restrict__ tri, int px, float v) {
    constexpr bool diag = (rowof(P) == colof(P));
    tri[P * TS2 + px] = diag ? (v + EPSR) : v;
}

template<int G, int... TT>
__device__ __forceinline__ void store_tri_group(float* __restrict__ tri, int px,
                                                const float (&acc)[68],
                                                std::integer_sequence<int, TT...>) {
    (store_tri_pair<G * 68 + TT>(tri, px, acc[TT]), ...);
}

// ---------------- fused kernel ----------------

union SMem {
    float stage[2][4096];      // 2 x 16 KB: [c'(0..1)*2048 + k*128 + px]
    float tri[136 * TS2];      // 71.3 KB; row = pair index, col = pixel
};

__global__ __launch_bounds__(256, 2)
void fused_gram_inv(const float* __restrict__ x, float* __restrict__ out) {
    __shared__ __align__(16) SMem sm;

    const int tid = threadIdx.x;
    const int lane = tid & 63;
    const int wv = tid >> 6;                  // 0..3
    const int G = wv & 1;                     // pair group (0: pairs 0-67, 1: 68-135)
    const int ph = wv >> 1;                   // pixel half (0: px 0-63, 1: px 64-127)
    const int px = ph * 64 + lane;            // this thread's pixel
    const int p0 = blockIdx.x * 128;
    const int b = blockIdx.x >> 7;            // 128 blocks per batch
    const int hw0 = p0 & 16383;

    // staging src: lane l covers k-row (l>>5), px (l&31)*4..+3  (16B/lane,
    // one instr = 2 k-rows x 128 px = 1 KB, lane-linear in LDS)
    const float* gbase = x + (size_t)b * 16777216 + hw0
                           + (size_t)(lane >> 5) * 16384 + (size_t)(lane & 31) * 4;

    float acc[68];
    #pragma unroll
    for (int t = 0; t < 68; ++t) acc[t] = 0.0f;

    // chunk t = channels {2t, 2t+1}; wave (ph,G) stages c' = ph, k in [8G, 8G+8)
    auto STAGE = [&](int bufi, int c0) {
        const float* gp = gbase + (size_t)(c0 + ph) * 262144
                                + (size_t)(G * 8) * 16384;
        #pragma unroll
        for (int q = 0; q < 4; ++q) {
            GLOAD_LDS16(gp + (size_t)(q * 2) * 16384,
                        &sm.stage[bufi][ph * 2048 + (G * 8 + q * 2) * 128]);
        }
    };

    // ---- phase 1: gram, dbuf pipeline (32 chunks of 2 c) ----
    STAGE(0, 0);
    for (int t = 0; t < 32; ++t) {
        __syncthreads();                              // vmcnt(0) drain + barrier
        if (t < 31) STAGE((t + 1) & 1, 2 * (t + 1));  // prefetch next chunk
        const float* buf = sm.stage[t & 1];
        if (G == 0) chunk_fma2<0>(buf, px, acc);
        else        chunk_fma2<1>(buf, px, acc);
    }
    __syncthreads();   // all stage reads done before aliasing stage as tri

    // ---- phase 2: acc -> tri (+EPS on diag); disjoint (row,col) per wave ----
    if (G == 0) store_tri_group<0>(sm.tri, px, acc, std::make_integer_sequence<int, 68>{});
    else        store_tri_group<1>(sm.tri, px, acc, std::make_integer_sequence<int, 68>{});
    __syncthreads();

    // ---- phase 3: waves 0,2 (G==0), lane = own px, REGISTER inversion ----
    if (G == 0) {
        float s[136];
        #pragma unroll
        for (int t = 0; t < 136; ++t) s[t] = sm.tri[t * TS2 + px];

        // Cholesky in place: off-diag = L[i][j], diag = 1/L[j][j]
        #pragma unroll
        for (int j = 0; j < 16; ++j) {
            float d = s[tidx(j, j)];
            #pragma unroll
            for (int q = 0; q < j; ++q) d = fmaf(-s[tidx(j, q)], s[tidx(j, q)], d);
            const float invd = 1.0f / sqrtf(d);
            s[tidx(j, j)] = invd;
            #pragma unroll
            for (int i = j + 1; i < 16; ++i) {
                float v = s[tidx(i, j)];
                #pragma unroll
                for (int q = 0; q < j; ++q) v = fmaf(-s[tidx(i, q)], s[tidx(j, q)], v);
                s[tidx(i, j)] = v * invd;
            }
        }

        // M = L^{-1} in place (diag already inverted)
        #pragma unroll
        for (int j = 0; j < 16; ++j) {
            #pragma unroll
            for (int i = j + 1; i < 16; ++i) {
                float sum = s[tidx(i, j)] * s[tidx(j, j)];
                #pragma unroll
                for (int q = j + 1; q < i; ++q)
                    sum = fmaf(s[tidx(i, q)], s[tidx(q, j)], sum);
                s[tidx(i, j)] = -s[tidx(i, i)] * sum;
            }
        }

        // A^{-1} = M^T M in place
        #pragma unroll
        for (int j = 0; j < 16; ++j) {
            #pragma unroll
            for (int i = j; i < 16; ++i) {
                float sum = 0.0f;
                #pragma unroll
                for (int q = i; q < 16; ++q)
                    sum = fmaf(s[tidx(q, i)], s[tidx(q, j)], sum);
                s[tidx(i, j)] = sum;
            }
        }

        // writeback
        #pragma unroll
        for (int t = 0; t < 136; ++t) sm.tri[t * TS2 + px] = s[t];
    }
    __syncthreads();

    // ---- phase 4: gather-store, thread = output element e, loop 128 px ----
    const int e = tid;                  // 0..255 -> (i,j)
    const int i = e >> 4, j = e & 15;
    const int hi = i > j ? i : j;
    const int lo = i + j - hi;
    const int trow = hi * (hi + 1) / 2 + lo;
    float* gout = out + (size_t)p0 * 256;
    #pragma unroll 8
    for (int a = 0; a < 128; ++a) {
        gout[(size_t)a * 256 + e] = sm.tri[trow * TS2 + a];
    }
}

extern "C" void kernel_launch(void* const* d_in, const int* in_sizes, int n_in,
                              void* d_out, int out_size, void* d_ws, size_t ws_size,
                              hipStream_t stream) {
    const float* x = (const float*)d_in[0];
    float* out = (float*)d_out;
    hipLaunchKernelGGL(fused_gram_inv, dim3(512), dim3(256), 0, stream, x, out);
}